// Round 19
// baseline (105.237 us; speedup 1.0000x reference)
//
#include <hip/hip_runtime.h>
#include <hip/hip_bf16.h>

#define NEV 131072
#define NF 128
#define NG 64
#define KIN 192      // NF + NG
#define NH 512
#define NOUT 256     // N_BRANCHES * NF
#define BM 64
#define NT 512
#define TILES 8
#define NPERS (NEV / (BM * TILES))   // 256 blocks = 1/CU
#define ABYTES 24576                 // one A tile (64 x 192 bf16, swizzle pad-free)
#define HBASE (2 * ABYTES)           // 49152
#define LDSTOT (HBASE + BM * NH * 2) // 114688 = 112KB: A0 | A1 | h

typedef __bf16 bf16x8 __attribute__((ext_vector_type(8)));
typedef __bf16 bf16x4 __attribute__((ext_vector_type(4)));
typedef float f32x4 __attribute__((ext_vector_type(4)));

// Swizzled LDS byte offsets: XOR (row&7)<<4 spreads rows across 16B slots.
__device__ __forceinline__ int a_off(int r, int cb) { return r * 384 + (cb ^ ((r & 7) << 4)); }
__device__ __forceinline__ int h_off(int r, int cb) { return r * 1024 + (cb ^ ((r & 7) << 4)); }

// ---- weight pre-pack into per-wave FRAGMENT ORDER (bf16), 1KB contiguous per
// wave fragment load. BYTE-IDENTICAL to rounds 3-18 (verified): 8 col-groups.
__global__ void pack_w(const float* __restrict__ W1, const float* __restrict__ W2,
                       __bf16* __restrict__ w1p, __bf16* __restrict__ w2p) {
    int t = blockIdx.x * blockDim.x + threadIdx.x;
    if (t < KIN * NH) {
        int j = t & 7;
        int lane = (t >> 3) & 63;
        int n = (t >> 9) & 3;
        int r = t >> 11;          // wc*6 + kk
        int kk = r % 6;
        int wc = r / 6;
        int lg = lane >> 4, lr = lane & 15;
        int k = kk * 32 + lg * 8 + j;
        int col = wc * 64 + n * 16 + lr;
        w1p[t] = (__bf16)W1[(size_t)k * NH + col];
    } else {
        int u = t - KIN * NH;
        if (u < NH * NOUT) {
            int j = u & 7;
            int lane = (u >> 3) & 63;
            int n = (u >> 9) & 1;
            int r = u >> 10;      // wc*16 + kk
            int kk = r & 15;
            int wc = r >> 4;
            int lg = lane >> 4, lr = lane & 15;
            int k = kk * 32 + lg * 8 + j;
            int col = wc * 32 + n * 16 + lr;
            w2p[u] = (__bf16)W2[(size_t)k * NOUT + col];
        }
    }
}

// ================= persistent: 256 blocks x 8 tiles of BM=64 ================
// LDS triple-region {A0, A1, h} removes the A/h overlay: next-tile staging
// overlaps GEMM1/GEMM2 compute (the ~27us serial stage term), and the
// GEMM1->epi1 barrier disappears (2 barriers/tile). 512 thr = 2 waves/EU ->
// 256-reg budget; GEMM1 peak live ~177 (acc 64 + stage 40 + a 16 + b 32 +
// addr) -> no spill by construction (r7's killer). All out-writes nt (r4's
// killer). Weight fragments rolling-prefetched (r17's lever).
__global__ __launch_bounds__(NT)
__attribute__((amdgpu_waves_per_eu(2, 2))) void fused_pers(
        const float* __restrict__ x, const float* __restrict__ gf,
        const __bf16* __restrict__ w1p, const float* __restrict__ b1,
        const __bf16* __restrict__ w2p, const float* __restrict__ b2,
        const int* __restrict__ idx, float* __restrict__ out) {
    extern __shared__ __align__(16) unsigned char smem[];

    const int tid = threadIdx.x;
    const int wc = tid >> 6;           // wave = col-group 0..7
    const int lane = tid & 63;
    const int lg = lane >> 4;
    const int lr = lane & 15;

    const f32x4* x4 = (const f32x4*)x;
    const f32x4* g4 = (const f32x4*)gf;
    f32x4* o4 = (f32x4*)out;
    const int xr = tid >> 5, xc = tid & 31;   // x staging: rows xr+16s, col xc
    const int gr = tid >> 4, gc = tid & 15;   // gf staging: rows gr+32s, col gc

    f32x4 xv[4], xs[4], gv[2];                // issue-early staging registers

    auto stage_issue = [&](int row0) {
#pragma unroll
        for (int s = 0; s < 4; ++s) {
            int e = row0 + xr + 16 * s;
            int p = idx[e];
            xv[s] = x4[(size_t)e * 32 + xc];
            xs[s] = xv[s];
            if (p != e) xs[s] = x4[(size_t)p * 32 + xc];   // exec-masked gather
        }
#pragma unroll
        for (int s = 0; s < 2; ++s) {
            int e = row0 + gr + 32 * s;
            int p = idx[e] & (NEV - 1);                    // parents_idxs % n_events
            gv[s] = g4[(size_t)p * 16 + gc];
        }
    };
    auto stage_commit = [&](int row0, int ab) {
#pragma unroll
        for (int s = 0; s < 4; ++s) {
            int r = xr + 16 * s;
            __builtin_nontemporal_store(xv[s], &o4[(size_t)(row0 + r) * 32 + xc]);  // out[0:NEV]=x
            bf16x4 tb = {(__bf16)xs[s][0], (__bf16)xs[s][1], (__bf16)xs[s][2], (__bf16)xs[s][3]};
            *(bf16x4*)(smem + ab + a_off(r, xc * 8)) = tb;
        }
#pragma unroll
        for (int s = 0; s < 2; ++s) {
            int r = gr + 32 * s;
            bf16x4 tb = {(__bf16)gv[s][0], (__bf16)gv[s][1], (__bf16)gv[s][2], (__bf16)gv[s][3]};
            *(bf16x4*)(smem + ab + a_off(r, 256 + gc * 8)) = tb;
        }
    };

    int row0 = blockIdx.x * (BM * TILES);

    // prologue: stage tile 0 into A0; prefetch W1 kk0
    stage_issue(row0);
    stage_commit(row0, 0);
    bf16x8 bcur[4];
    {
        const __bf16* wp = w1p;
        asm volatile("" : "+s"(wp));
#pragma unroll
        for (int n = 0; n < 4; ++n)
            bcur[n] = *(const bf16x8*)(wp + (size_t)((wc * 6 + 0) * 4 + n) * 512 + lane * 8);
    }
    __syncthreads();

    for (int t = 0; t < TILES; ++t) {
        const int ab = (t & 1) ? ABYTES : 0;       // A buffer this tile reads
        const int nb = (t & 1) ? 0 : ABYTES;       // A buffer next tile's stage fills

        // issue next-tile gather loads: HBM/L3 latency hides under GEMM1
        if (t + 1 < TILES) stage_issue(row0 + BM);

        // ---- GEMM1 (operand-swapped), rolling 1-deep W1 prefetch
        f32x4 acc1T[4][4] = {};
#pragma unroll
        for (int kk = 0; kk < KIN / 32; ++kk) {
            bf16x8 bnxt[4];
            if (kk + 1 < KIN / 32) {
                const __bf16* wp = w1p;
                asm volatile("" : "+s"(wp));
#pragma unroll
                for (int n = 0; n < 4; ++n)
                    bnxt[n] = *(const bf16x8*)(wp + (size_t)((wc * 6 + kk + 1) * 4 + n) * 512 + lane * 8);
            }
            int kbyte = kk * 64 + lg * 16;
            bf16x8 a[4];
#pragma unroll
            for (int m = 0; m < 4; ++m)
                a[m] = *(const bf16x8*)(smem + ab + a_off(m * 16 + lr, kbyte));
            __builtin_amdgcn_s_setprio(1);
#pragma unroll
            for (int n = 0; n < 4; ++n)
#pragma unroll
                for (int m = 0; m < 4; ++m)
                    acc1T[n][m] = __builtin_amdgcn_mfma_f32_16x16x32_bf16(bcur[n], a[m], acc1T[n][m], 0, 0, 0);
            __builtin_amdgcn_s_setprio(0);
            if (kk + 1 < KIN / 32) {
#pragma unroll
                for (int n = 0; n < 4; ++n) bcur[n] = bnxt[n];
            }
            __builtin_amdgcn_sched_barrier(0);
        }

        // commit next-tile A into the OTHER buffer (disjoint region: no barrier)
        if (t + 1 < TILES) stage_commit(row0 + BM, nb);

        // ---- epi1: bias + leaky_relu -> h (h region disjoint from A: no barrier)
#pragma unroll
        for (int n = 0; n < 4; ++n) {
            int c0 = wc * 64 + n * 16 + lg * 4;
            f32x4 bb = *(const f32x4*)(b1 + c0);
#pragma unroll
            for (int m = 0; m < 4; ++m) {
                int e = m * 16 + lr;
                bf16x4 tb;
#pragma unroll
                for (int i = 0; i < 4; ++i) {
                    float v = acc1T[n][m][i] + bb[i];
                    v = (v >= 0.f) ? v : 0.01f * v;
                    tb[i] = (__bf16)v;
                }
                *(bf16x4*)(smem + HBASE + h_off(e, c0 * 2)) = tb;
            }
        }

        // W2 kk0 prefetch: lands during barrier
        bf16x8 ccur[2];
        {
            const __bf16* wp = w2p;
            asm volatile("" : "+s"(wp));
#pragma unroll
            for (int n = 0; n < 2; ++n)
                ccur[n] = *(const bf16x8*)(wp + (size_t)((wc * 16 + 0) * 2 + n) * 512 + lane * 8);
        }
        __syncthreads();   // h ready (and A-next committed)

        // ---- GEMM2 (operand-swapped), rolling 1-deep W2 prefetch
        f32x4 acc2T[2][4] = {};
#pragma unroll
        for (int kk = 0; kk < NH / 32; ++kk) {
            bf16x8 cnxt[2];
            if (kk + 1 < NH / 32) {
                const __bf16* wp = w2p;
                asm volatile("" : "+s"(wp));
#pragma unroll
                for (int n = 0; n < 2; ++n)
                    cnxt[n] = *(const bf16x8*)(wp + (size_t)((wc * 16 + kk + 1) * 2 + n) * 512 + lane * 8);
            }
            int kbyte = kk * 64 + lg * 16;
            bf16x8 a2[4];
#pragma unroll
            for (int m = 0; m < 4; ++m)
                a2[m] = *(const bf16x8*)(smem + HBASE + h_off(m * 16 + lr, kbyte));
            __builtin_amdgcn_s_setprio(1);
#pragma unroll
            for (int n = 0; n < 2; ++n)
#pragma unroll
                for (int m = 0; m < 4; ++m)
                    acc2T[n][m] = __builtin_amdgcn_mfma_f32_16x16x32_bf16(ccur[n], a2[m], acc2T[n][m], 0, 0, 0);
            __builtin_amdgcn_s_setprio(0);
            if (kk + 1 < NH / 32) {
#pragma unroll
                for (int n = 0; n < 2; ++n) ccur[n] = cnxt[n];
            }
            __builtin_amdgcn_sched_barrier(0);
        }

        // ---- epi2: bias + branch-split, nt float4 stores
        float* ob = out + ((size_t)NEV * (1 + (wc >> 2))) * NF;
#pragma unroll
        for (int m = 0; m < 4; ++m) {
            size_t ebase = (size_t)(row0 + m * 16 + lr) * NF;
#pragma unroll
            for (int n = 0; n < 2; ++n) {
                int col = wc * 32 + n * 16 + lg * 4;
                f32x4 bb = *(const f32x4*)(b2 + col);
                f32x4 v = acc2T[n][m] + bb;
                __builtin_nontemporal_store(v, (f32x4*)(ob + ebase + (col & 127)));
            }
        }

        // W1 kk0 prefetch for next tile (L2-hot; lands during barrier)
        if (t + 1 < TILES) {
            const __bf16* wp = w1p;
            asm volatile("" : "+s"(wp));
#pragma unroll
            for (int n = 0; n < 4; ++n)
                bcur[n] = *(const bf16x8*)(wp + (size_t)((wc * 6 + 0) * 4 + n) * 512 + lane * 8);
        }
        __syncthreads();   // h free for next epi1
        row0 += BM;
    }
}

// ================= round-5 monolith (fallback paths) =========================
template <bool TW>
__global__ __launch_bounds__(512, 2) void fused_mlp(
        const float* __restrict__ x, const float* __restrict__ gf,
        const __bf16* __restrict__ w1p, const float* __restrict__ W1f,
        const float* __restrict__ b1,
        const __bf16* __restrict__ w2p, const float* __restrict__ W2f,
        const float* __restrict__ b2,
        const int* __restrict__ idx,
        float* __restrict__ out) {
    __shared__ __align__(16) unsigned char smem[65536];

    const int tid = threadIdx.x;
    const int wid = tid >> 6;
    const int lane = tid & 63;
    const int lg = lane >> 4;
    const int lr = lane & 15;
    const int row0 = blockIdx.x * 64;

    bf16x8 b1r[KIN / 32][4];
#pragma unroll
    for (int kk = 0; kk < KIN / 32; ++kk)
#pragma unroll
        for (int n = 0; n < 4; ++n) {
            if (TW) {
                b1r[kk][n] = *(const bf16x8*)(w1p + (size_t)(((wid * 6 + kk) * 4 + n) * 64 + lane) * 8);
            } else {
                int col = wid * 64 + n * 16 + lr;
                const float* wcp = W1f + (size_t)(kk * 32 + lg * 8) * NH + col;
#pragma unroll
                for (int i = 0; i < 8; ++i) b1r[kk][n][i] = (__bf16)wcp[(size_t)i * NH];
            }
        }

    const f32x4* x4 = (const f32x4*)x;
    const f32x4* g4 = (const f32x4*)gf;
    f32x4* o4 = (f32x4*)out;
    for (int q = tid; q < 64 * (NF / 4); q += 512) {
        int r = q >> 5, c4 = q & 31;
        int e = row0 + r;
        int p = idx[e];
        f32x4 v = x4[(size_t)e * 32 + c4];
        __builtin_nontemporal_store(v, &o4[(size_t)e * 32 + c4]);
        f32x4 vs = v;
        if (p != e) vs = x4[(size_t)p * 32 + c4];
        bf16x4 tb = {(__bf16)vs[0], (__bf16)vs[1], (__bf16)vs[2], (__bf16)vs[3]};
        *(bf16x4*)(smem + a_off(r, c4 * 8)) = tb;
    }
    for (int q = tid; q < 64 * (NG / 4); q += 512) {
        int r = q >> 4, c4 = q & 15;
        int e = row0 + r;
        int p = idx[e] & (NEV - 1);
        f32x4 vs = g4[(size_t)p * 16 + c4];
        bf16x4 tb = {(__bf16)vs[0], (__bf16)vs[1], (__bf16)vs[2], (__bf16)vs[3]};
        *(bf16x4*)(smem + a_off(r, 256 + c4 * 8)) = tb;
    }
    __syncthreads();

    f32x4 acc1T[4][4] = {};
#pragma unroll
    for (int kk = 0; kk < KIN / 32; ++kk) {
        int kbyte = kk * 64 + lg * 16;
        bf16x8 a[4];
#pragma unroll
        for (int m = 0; m < 4; ++m)
            a[m] = *(const bf16x8*)(smem + a_off(m * 16 + lr, kbyte));
        __builtin_amdgcn_s_setprio(1);
#pragma unroll
        for (int n = 0; n < 4; ++n)
#pragma unroll
            for (int m = 0; m < 4; ++m)
                acc1T[n][m] = __builtin_amdgcn_mfma_f32_16x16x32_bf16(b1r[kk][n], a[m], acc1T[n][m], 0, 0, 0);
        __builtin_amdgcn_s_setprio(0);
    }

    bf16x8 b2r[NH / 32][2];
#pragma unroll
    for (int kk = 0; kk < NH / 32; ++kk)
#pragma unroll
        for (int n = 0; n < 2; ++n) {
            if (TW) {
                b2r[kk][n] = *(const bf16x8*)(w2p + (size_t)(((wid * 16 + kk) * 2 + n) * 64 + lane) * 8);
            } else {
                int col = wid * 32 + n * 16 + lr;
                const float* wcp = W2f + (size_t)(kk * 32 + lg * 8) * NOUT + col;
#pragma unroll
                for (int i = 0; i < 8; ++i) b2r[kk][n][i] = (__bf16)wcp[(size_t)i * NOUT];
            }
        }

    __syncthreads();

#pragma unroll
    for (int n = 0; n < 4; ++n) {
        f32x4 bb = *(const f32x4*)(b1 + wid * 64 + n * 16 + lg * 4);
        int cb = (wid * 64 + n * 16 + lg * 4) * 2;
#pragma unroll
        for (int m = 0; m < 4; ++m) {
            int e = m * 16 + lr;
            bf16x4 tb;
#pragma unroll
            for (int i = 0; i < 4; ++i) {
                float v = acc1T[n][m][i] + bb[i];
                v = (v >= 0.f) ? v : 0.01f * v;
                tb[i] = (__bf16)v;
            }
            *(bf16x4*)(smem + h_off(e, cb)) = tb;
        }
    }
    __syncthreads();

    f32x4 acc2T[2][4] = {};
#pragma unroll
    for (int kk = 0; kk < NH / 32; ++kk) {
        int kbyte = kk * 64 + lg * 16;
        bf16x8 a2[4];
#pragma unroll
        for (int m = 0; m < 4; ++m)
            a2[m] = *(const bf16x8*)(smem + h_off(m * 16 + lr, kbyte));
        __builtin_amdgcn_s_setprio(1);
#pragma unroll
        for (int n = 0; n < 2; ++n)
#pragma unroll
            for (int m = 0; m < 4; ++m)
                acc2T[n][m] = __builtin_amdgcn_mfma_f32_16x16x32_bf16(b2r[kk][n], a2[m], acc2T[n][m], 0, 0, 0);
        __builtin_amdgcn_s_setprio(0);
    }

    float* ob = out + ((size_t)NEV * (1 + (wid >> 2))) * NF;
#pragma unroll
    for (int m = 0; m < 4; ++m) {
        size_t ebase = (size_t)(row0 + m * 16 + lr) * NF;
#pragma unroll
        for (int n = 0; n < 2; ++n) {
            int col = wid * 32 + n * 16 + lg * 4;
            f32x4 bb = *(const f32x4*)(b2 + col);
            f32x4 v = acc2T[n][m] + bb;
            __builtin_nontemporal_store(v, (f32x4*)(ob + ebase + (col & 127)));
        }
    }
}

extern "C" void kernel_launch(void* const* d_in, const int* in_sizes, int n_in,
                              void* d_out, int out_size, void* d_ws, size_t ws_size,
                              hipStream_t stream) {
    const float* x  = (const float*)d_in[0];
    const float* gf = (const float*)d_in[1];
    const float* W1 = (const float*)d_in[2];
    const float* b1 = (const float*)d_in[3];
    const float* W2 = (const float*)d_in[4];
    const float* b2 = (const float*)d_in[5];
    const int*  idx = (const int*)d_in[6];
    float* out = (float*)d_out;

    const size_t wbytes = (size_t)(KIN * NH + NH * NOUT) * sizeof(__bf16);  // 458752
    int tot = KIN * NH + NH * NOUT;

    if (ws_size >= wbytes) {
        __bf16* w1p = (__bf16*)d_ws;
        __bf16* w2p = w1p + KIN * NH;
        pack_w<<<(tot + 511) / 512, 512, 0, stream>>>(W1, W2, w1p, w2p);
        hipError_t st = hipFuncSetAttribute(
            (const void*)fused_pers, hipFuncAttributeMaxDynamicSharedMemorySize, LDSTOT);
        if (st == hipSuccess) {
            fused_pers<<<NPERS, NT, LDSTOT, stream>>>(x, gf, w1p, b1, w2p, b2, idx, out);
        } else {
            fused_mlp<true><<<NEV / 64, 512, 0, stream>>>(x, gf, w1p, nullptr, b1,
                                                          w2p, nullptr, b2, idx, out);
        }
    } else {
        fused_mlp<false><<<NEV / 64, 512, 0, stream>>>(x, gf, nullptr, W1, b1,
                                                       nullptr, W2, b2, idx, out);
    }
}

// Round 20
// 100.845 us; speedup vs baseline: 1.0436x; 1.0436x over previous
//
#include <hip/hip_runtime.h>
#include <hip/hip_bf16.h>

#define NEV 131072
#define NF 128
#define NG 64
#define KIN 192      // NF + NG
#define NH 512
#define NOUT 256     // N_BRANCHES * NF
#define BM 128
#define NT 512
#define NBLK (NEV / BM)        // 1024
#define LDS128 131072

typedef __bf16 bf16x8 __attribute__((ext_vector_type(8)));
typedef __bf16 bf16x4 __attribute__((ext_vector_type(4)));
typedef float f32x4 __attribute__((ext_vector_type(4)));

// Swizzled LDS byte offsets: XOR (row&7)<<4 spreads rows across 16B slots.
__device__ __forceinline__ int a_off(int r, int cb) { return r * 384 + (cb ^ ((r & 7) << 4)); }
__device__ __forceinline__ int h_off(int r, int cb) { return r * 1024 + (cb ^ ((r & 7) << 4)); }

// ---- weight pre-pack into per-wave FRAGMENT ORDER (bf16), 1KB contiguous per
// wave fragment load. BYTE-IDENTICAL to rounds 3-18 (verified).
__global__ void pack_w(const float* __restrict__ W1, const float* __restrict__ W2,
                       __bf16* __restrict__ w1p, __bf16* __restrict__ w2p) {
    int t = blockIdx.x * blockDim.x + threadIdx.x;
    if (t < KIN * NH) {
        int j = t & 7;
        int lane = (t >> 3) & 63;
        int n = (t >> 9) & 3;
        int r = t >> 11;          // wc*6 + kk
        int kk = r % 6;
        int wc = r / 6;
        int lg = lane >> 4, lr = lane & 15;
        int k = kk * 32 + lg * 8 + j;
        int col = wc * 64 + n * 16 + lr;
        w1p[t] = (__bf16)W1[(size_t)k * NH + col];
    } else {
        int u = t - KIN * NH;
        if (u < NH * NOUT) {
            int j = u & 7;
            int lane = (u >> 3) & 63;
            int n = (u >> 9) & 1;
            int r = u >> 10;      // wc*16 + kk
            int kk = r & 15;
            int wc = r >> 4;
            int lg = lane >> 4, lr = lane & 15;
            int k = kk * 32 + lg * 8 + j;
            int col = wc * 32 + n * 16 + lr;
            w2p[u] = (__bf16)W2[(size_t)k * NOUT + col];
        }
    }
}

// ================= BM=128, 512 threads: 8 waves = 8 col-groups, all rows ====
// r18 (best 102.2us) + DEPTH-2 rolling weight prefetch: depth-1 issued loads
// only ~160-260cy before use (< L2 latency ~200-300cy) -> partial cover.
// Depth-2 = ~320-520cy ahead = full cover. Register check vs 256 budget:
// GEMM1 peak = acc 128 AGPR + a[8] 32 + queue 48 + addr ~25 = 233 < 256.
// Fully-unrolled loops keep queue indices compile-time (rule-#20 safe).
// r19 lesson folded in: BM=128 weight reuse beats stage overlap; persistence
// retired (BM=64 reuse loss > overlap gain; A-dbuf+h don't fit 160KB at 128).
__global__ __launch_bounds__(NT)
__attribute__((amdgpu_waves_per_eu(2, 2))) void fused128(
        const float* __restrict__ x, const float* __restrict__ gf,
        const __bf16* __restrict__ w1p, const float* __restrict__ b1,
        const __bf16* __restrict__ w2p, const float* __restrict__ b2,
        const int* __restrict__ idx, float* __restrict__ out) {
    extern __shared__ __align__(16) unsigned char smem[];  // A [0,48K) overlaid by h [0,128K)

    const int tid = threadIdx.x;
    const int wc = tid >> 6;           // wave = col-group 0..7
    const int lane = tid & 63;
    const int lg = lane >> 4;
    const int lr = lane & 15;
    const int row0 = blockIdx.x * BM;

    // ---- GEMM1 kk=0,1 weight fragments: issued FIRST, hide under stage
    bf16x8 bq0[4], bq1[4];
    {
        const __bf16* wp = w1p;
        asm volatile("" : "+s"(wp));
#pragma unroll
        for (int n = 0; n < 4; ++n)
            bq0[n] = *(const bf16x8*)(wp + (size_t)((wc * 6 + 0) * 4 + n) * 512 + lane * 8);
#pragma unroll
        for (int n = 0; n < 4; ++n)
            bq1[n] = *(const bf16x8*)(wp + (size_t)((wc * 6 + 1) * 4 + n) * 512 + lane * 8);
    }

    // ---- stage A = [x | gf] bf16 into LDS (swizzled); fused x->out copy (nt)
    const f32x4* x4 = (const f32x4*)x;
    const f32x4* g4 = (const f32x4*)gf;
    f32x4* o4 = (f32x4*)out;
#pragma unroll
    for (int q = tid; q < BM * (NF / 4); q += NT) {
        int r = q >> 5, c4 = q & 31;
        int e = row0 + r;
        int p = idx[e];
        f32x4 v = x4[(size_t)e * 32 + c4];
        __builtin_nontemporal_store(v, &o4[(size_t)e * 32 + c4]);   // out[0:NEV] = x
        f32x4 vs = v;
        if (p != e) vs = x4[(size_t)p * 32 + c4];   // exec-masked gather
        bf16x4 tb = {(__bf16)vs[0], (__bf16)vs[1], (__bf16)vs[2], (__bf16)vs[3]};
        *(bf16x4*)(smem + a_off(r, c4 * 8)) = tb;
    }
#pragma unroll
    for (int q = tid; q < BM * (NG / 4); q += NT) {
        int r = q >> 4, c4 = q & 15;
        int e = row0 + r;
        int p = idx[e] & (NEV - 1);                 // parents_idxs % n_events
        f32x4 vs = g4[(size_t)p * 16 + c4];
        bf16x4 tb = {(__bf16)vs[0], (__bf16)vs[1], (__bf16)vs[2], (__bf16)vs[3]};
        *(bf16x4*)(smem + a_off(r, 256 + c4 * 8)) = tb;
    }
    __syncthreads();

    // ---- GEMM1 (operand-swapped): wave owns 64 hidden cols x ALL 128 rows.
    //      Flat a[8] ds_reads + DEPTH-2 rolling B prefetch.
    f32x4 acc1T[4][8] = {};
#pragma unroll
    for (int kk = 0; kk < KIN / 32; ++kk) {
        bf16x8 bq2[4];
        if (kk + 2 < KIN / 32) {
            const __bf16* wp = w1p;
            asm volatile("" : "+s"(wp));
#pragma unroll
            for (int n = 0; n < 4; ++n)
                bq2[n] = *(const bf16x8*)(wp + (size_t)((wc * 6 + kk + 2) * 4 + n) * 512 + lane * 8);
        }
        int kbyte = kk * 64 + lg * 16;
        bf16x8 a[8];
#pragma unroll
        for (int m = 0; m < 8; ++m)
            a[m] = *(const bf16x8*)(smem + a_off(m * 16 + lr, kbyte));
        __builtin_amdgcn_s_setprio(1);
#pragma unroll
        for (int n = 0; n < 4; ++n)
#pragma unroll
            for (int m = 0; m < 8; ++m)
                acc1T[n][m] = __builtin_amdgcn_mfma_f32_16x16x32_bf16(bq0[n], a[m], acc1T[n][m], 0, 0, 0);
        __builtin_amdgcn_s_setprio(0);
#pragma unroll
        for (int n = 0; n < 4; ++n) { bq0[n] = bq1[n]; bq1[n] = bq2[n]; }
        __builtin_amdgcn_sched_barrier(0);   // depth-2 pipeline only
    }

    // ---- GEMM2 kk=0,1 weight fragments: issue before barrier, hide under epi1
    bf16x8 cq0[2], cq1[2];
    {
        const __bf16* wp = w2p;
        asm volatile("" : "+s"(wp));
#pragma unroll
        for (int n = 0; n < 2; ++n)
            cq0[n] = *(const bf16x8*)(wp + (size_t)((wc * 16 + 0) * 2 + n) * 512 + lane * 8);
#pragma unroll
        for (int n = 0; n < 2; ++n)
            cq1[n] = *(const bf16x8*)(wp + (size_t)((wc * 16 + 1) * 2 + n) * 512 + lane * 8);
    }
    __syncthreads();   // A fully read; smem becomes h (128KB)

    // ---- epi1: bias + leaky_relu -> h bf16 (vectorized ds_write_b64)
#pragma unroll
    for (int n = 0; n < 4; ++n) {
        int c0 = wc * 64 + n * 16 + lg * 4;
        f32x4 bb = *(const f32x4*)(b1 + c0);
#pragma unroll
        for (int m = 0; m < 8; ++m) {
            int e = m * 16 + lr;
            bf16x4 tb;
#pragma unroll
            for (int i = 0; i < 4; ++i) {
                float v = acc1T[n][m][i] + bb[i];
                v = (v >= 0.f) ? v : 0.01f * v;
                tb[i] = (__bf16)v;
            }
            *(bf16x4*)(smem + h_off(e, c0 * 2)) = tb;
        }
    }
    __syncthreads();   // h ready

    // ---- GEMM2 (operand-swapped): wave owns 32 out cols x ALL 128 rows.
    //      Flat a2[8] ds_reads + DEPTH-2 rolling prefetch (16 kk iterations).
    f32x4 acc2T[2][8] = {};
#pragma unroll
    for (int kk = 0; kk < NH / 32; ++kk) {
        bf16x8 cq2[2];
        if (kk + 2 < NH / 32) {
            const __bf16* wp = w2p;
            asm volatile("" : "+s"(wp));
#pragma unroll
            for (int n = 0; n < 2; ++n)
                cq2[n] = *(const bf16x8*)(wp + (size_t)((wc * 16 + kk + 2) * 2 + n) * 512 + lane * 8);
        }
        int kbyte = kk * 64 + lg * 16;
        bf16x8 a2[8];
#pragma unroll
        for (int m = 0; m < 8; ++m)
            a2[m] = *(const bf16x8*)(smem + h_off(m * 16 + lr, kbyte));
        __builtin_amdgcn_s_setprio(1);
#pragma unroll
        for (int n = 0; n < 2; ++n)
#pragma unroll
            for (int m = 0; m < 8; ++m)
                acc2T[n][m] = __builtin_amdgcn_mfma_f32_16x16x32_bf16(cq0[n], a2[m], acc2T[n][m], 0, 0, 0);
        __builtin_amdgcn_s_setprio(0);
#pragma unroll
        for (int n = 0; n < 2; ++n) { cq0[n] = cq1[n]; cq1[n] = cq2[n]; }
        __builtin_amdgcn_sched_barrier(0);   // depth-2 pipeline only
    }

    // ---- epi2: bias + branch-split, nt float4 stores, m-outer so both 64B
    //      halves of each 128B out-line issue back-to-back
    float* ob = out + ((size_t)NEV * (1 + (wc >> 2))) * NF;
#pragma unroll
    for (int m = 0; m < 8; ++m) {
        size_t ebase = (size_t)(row0 + m * 16 + lr) * NF;
#pragma unroll
        for (int n = 0; n < 2; ++n) {
            int col = wc * 32 + n * 16 + lg * 4;
            f32x4 bb = *(const f32x4*)(b2 + col);
            f32x4 v = acc2T[n][m] + bb;
            __builtin_nontemporal_store(v, (f32x4*)(ob + ebase + (col & 127)));
        }
    }
}

// ================= round-5 monolith (fallback paths) =========================
template <bool TW>
__global__ __launch_bounds__(512, 2) void fused_mlp(
        const float* __restrict__ x, const float* __restrict__ gf,
        const __bf16* __restrict__ w1p, const float* __restrict__ W1f,
        const float* __restrict__ b1,
        const __bf16* __restrict__ w2p, const float* __restrict__ W2f,
        const float* __restrict__ b2,
        const int* __restrict__ idx,
        float* __restrict__ out) {
    __shared__ __align__(16) unsigned char smem[65536];

    const int tid = threadIdx.x;
    const int wid = tid >> 6;
    const int lane = tid & 63;
    const int lg = lane >> 4;
    const int lr = lane & 15;
    const int row0 = blockIdx.x * 64;

    bf16x8 b1r[KIN / 32][4];
#pragma unroll
    for (int kk = 0; kk < KIN / 32; ++kk)
#pragma unroll
        for (int n = 0; n < 4; ++n) {
            if (TW) {
                b1r[kk][n] = *(const bf16x8*)(w1p + (size_t)(((wid * 6 + kk) * 4 + n) * 64 + lane) * 8);
            } else {
                int col = wid * 64 + n * 16 + lr;
                const float* wcp = W1f + (size_t)(kk * 32 + lg * 8) * NH + col;
#pragma unroll
                for (int i = 0; i < 8; ++i) b1r[kk][n][i] = (__bf16)wcp[(size_t)i * NH];
            }
        }

    const f32x4* x4 = (const f32x4*)x;
    const f32x4* g4 = (const f32x4*)gf;
    f32x4* o4 = (f32x4*)out;
    for (int q = tid; q < 64 * (NF / 4); q += 512) {
        int r = q >> 5, c4 = q & 31;
        int e = row0 + r;
        int p = idx[e];
        f32x4 v = x4[(size_t)e * 32 + c4];
        __builtin_nontemporal_store(v, &o4[(size_t)e * 32 + c4]);
        f32x4 vs = v;
        if (p != e) vs = x4[(size_t)p * 32 + c4];
        bf16x4 tb = {(__bf16)vs[0], (__bf16)vs[1], (__bf16)vs[2], (__bf16)vs[3]};
        *(bf16x4*)(smem + a_off(r, c4 * 8)) = tb;
    }
    for (int q = tid; q < 64 * (NG / 4); q += 512) {
        int r = q >> 4, c4 = q & 15;
        int e = row0 + r;
        int p = idx[e] & (NEV - 1);
        f32x4 vs = g4[(size_t)p * 16 + c4];
        bf16x4 tb = {(__bf16)vs[0], (__bf16)vs[1], (__bf16)vs[2], (__bf16)vs[3]};
        *(bf16x4*)(smem + a_off(r, 256 + c4 * 8)) = tb;
    }
    __syncthreads();

    f32x4 acc1T[4][4] = {};
#pragma unroll
    for (int kk = 0; kk < KIN / 32; ++kk) {
        int kbyte = kk * 64 + lg * 16;
        bf16x8 a[4];
#pragma unroll
        for (int m = 0; m < 4; ++m)
            a[m] = *(const bf16x8*)(smem + a_off(m * 16 + lr, kbyte));
        __builtin_amdgcn_s_setprio(1);
#pragma unroll
        for (int n = 0; n < 4; ++n)
#pragma unroll
            for (int m = 0; m < 4; ++m)
                acc1T[n][m] = __builtin_amdgcn_mfma_f32_16x16x32_bf16(b1r[kk][n], a[m], acc1T[n][m], 0, 0, 0);
        __builtin_amdgcn_s_setprio(0);
    }

    bf16x8 b2r[NH / 32][2];
#pragma unroll
    for (int kk = 0; kk < NH / 32; ++kk)
#pragma unroll
        for (int n = 0; n < 2; ++n) {
            if (TW) {
                b2r[kk][n] = *(const bf16x8*)(w2p + (size_t)(((wid * 16 + kk) * 2 + n) * 64 + lane) * 8);
            } else {
                int col = wid * 32 + n * 16 + lr;
                const float* wcp = W2f + (size_t)(kk * 32 + lg * 8) * NOUT + col;
#pragma unroll
                for (int i = 0; i < 8; ++i) b2r[kk][n][i] = (__bf16)wcp[(size_t)i * NOUT];
            }
        }

    __syncthreads();

#pragma unroll
    for (int n = 0; n < 4; ++n) {
        f32x4 bb = *(const f32x4*)(b1 + wid * 64 + n * 16 + lg * 4);
        int cb = (wid * 64 + n * 16 + lg * 4) * 2;
#pragma unroll
        for (int m = 0; m < 4; ++m) {
            int e = m * 16 + lr;
            bf16x4 tb;
#pragma unroll
            for (int i = 0; i < 4; ++i) {
                float v = acc1T[n][m][i] + bb[i];
                v = (v >= 0.f) ? v : 0.01f * v;
                tb[i] = (__bf16)v;
            }
            *(bf16x4*)(smem + h_off(e, cb)) = tb;
        }
    }
    __syncthreads();

    f32x4 acc2T[2][4] = {};
#pragma unroll
    for (int kk = 0; kk < NH / 32; ++kk) {
        int kbyte = kk * 64 + lg * 16;
        bf16x8 a2[4];
#pragma unroll
        for (int m = 0; m < 4; ++m)
            a2[m] = *(const bf16x8*)(smem + h_off(m * 16 + lr, kbyte));
        __builtin_amdgcn_s_setprio(1);
#pragma unroll
        for (int n = 0; n < 2; ++n)
#pragma unroll
            for (int m = 0; m < 4; ++m)
                acc2T[n][m] = __builtin_amdgcn_mfma_f32_16x16x32_bf16(b2r[kk][n], a2[m], acc2T[n][m], 0, 0, 0);
        __builtin_amdgcn_s_setprio(0);
    }

    float* ob = out + ((size_t)NEV * (1 + (wid >> 2))) * NF;
#pragma unroll
    for (int m = 0; m < 4; ++m) {
        size_t ebase = (size_t)(row0 + m * 16 + lr) * NF;
#pragma unroll
        for (int n = 0; n < 2; ++n) {
            int col = wid * 32 + n * 16 + lg * 4;
            f32x4 bb = *(const f32x4*)(b2 + col);
            f32x4 v = acc2T[n][m] + bb;
            __builtin_nontemporal_store(v, (f32x4*)(ob + ebase + (col & 127)));
        }
    }
}

extern "C" void kernel_launch(void* const* d_in, const int* in_sizes, int n_in,
                              void* d_out, int out_size, void* d_ws, size_t ws_size,
                              hipStream_t stream) {
    const float* x  = (const float*)d_in[0];
    const float* gf = (const float*)d_in[1];
    const float* W1 = (const float*)d_in[2];
    const float* b1 = (const float*)d_in[3];
    const float* W2 = (const float*)d_in[4];
    const float* b2 = (const float*)d_in[5];
    const int*  idx = (const int*)d_in[6];
    float* out = (float*)d_out;

    const size_t wbytes = (size_t)(KIN * NH + NH * NOUT) * sizeof(__bf16);  // 458752
    int tot = KIN * NH + NH * NOUT;

    if (ws_size >= wbytes) {
        __bf16* w1p = (__bf16*)d_ws;
        __bf16* w2p = w1p + KIN * NH;
        pack_w<<<(tot + 511) / 512, 512, 0, stream>>>(W1, W2, w1p, w2p);
        hipError_t st = hipFuncSetAttribute(
            (const void*)fused128, hipFuncAttributeMaxDynamicSharedMemorySize, LDS128);
        if (st == hipSuccess) {
            fused128<<<NBLK, NT, LDS128, stream>>>(x, gf, w1p, b1, w2p, b2, idx, out);
        } else {
            fused_mlp<true><<<NEV / 64, 512, 0, stream>>>(x, gf, w1p, nullptr, b1,
                                                          w2p, nullptr, b2, idx, out);
        }
    } else {
        fused_mlp<false><<<NEV / 64, 512, 0, stream>>>(x, gf, nullptr, W1, b1,
                                                       nullptr, W2, b2, idx, out);
    }
}